// Round 1
// baseline (3275.464 us; speedup 1.0000x reference)
//
#include <hip/hip_runtime.h>
#include <hip/hip_bf16.h>
#include <math.h>

#define B_   2
#define S_   2048
#define HID_ 2048
#define NH_  16
#define HD_  128
#define QKV_ (3 * NH_ * HD_)   // 6144
#define EPS_ 1e-5f

// ---------------------------------------------------------------------------
// GEMM (NT): C[M,N] = A[M,K] * B[N,K]^T, all fp32 row-major, M,N % 128 == 0,
// K % 16 == 0. 128x128 block tile, 16 K-slice, 8x8 microtile per thread.
// ---------------------------------------------------------------------------
#define BM 128
#define BN 128
#define BK 16

__global__ __launch_bounds__(256) void gemm_nt(const float* __restrict__ A,
                                               const float* __restrict__ B,
                                               float* __restrict__ C,
                                               int M, int N, int K) {
    __shared__ float As[BK][BM + 4];   // As[k][m], +4 pad breaks write conflicts
    __shared__ float Bs[BK][BN + 4];

    const int tid = threadIdx.x;
    const int tx = tid & 15;    // n dim, 16 threads
    const int ty = tid >> 4;    // m dim, 16 threads
    const int m0 = blockIdx.y * BM;
    const int n0 = blockIdx.x * BN;

    float acc[8][8] = {};

    for (int k0 = 0; k0 < K; k0 += BK) {
        // stage A tile: 512 float4, 2 per thread
#pragma unroll
        for (int i = 0; i < 2; ++i) {
            int f   = tid + i * 256;
            int row = f >> 2;     // 0..127
            int kc  = (f & 3) * 4;
            float4 v = *reinterpret_cast<const float4*>(
                &A[(size_t)(m0 + row) * K + k0 + kc]);
            As[kc + 0][row] = v.x;
            As[kc + 1][row] = v.y;
            As[kc + 2][row] = v.z;
            As[kc + 3][row] = v.w;
        }
#pragma unroll
        for (int i = 0; i < 2; ++i) {
            int f   = tid + i * 256;
            int row = f >> 2;
            int kc  = (f & 3) * 4;
            float4 v = *reinterpret_cast<const float4*>(
                &B[(size_t)(n0 + row) * K + k0 + kc]);
            Bs[kc + 0][row] = v.x;
            Bs[kc + 1][row] = v.y;
            Bs[kc + 2][row] = v.z;
            Bs[kc + 3][row] = v.w;
        }
        __syncthreads();

#pragma unroll
        for (int kk = 0; kk < BK; ++kk) {
            float4 a0 = *reinterpret_cast<const float4*>(&As[kk][ty * 4]);
            float4 a1 = *reinterpret_cast<const float4*>(&As[kk][64 + ty * 4]);
            float4 b0 = *reinterpret_cast<const float4*>(&Bs[kk][tx * 4]);
            float4 b1 = *reinterpret_cast<const float4*>(&Bs[kk][64 + tx * 4]);
            float a[8] = {a0.x, a0.y, a0.z, a0.w, a1.x, a1.y, a1.z, a1.w};
            float b[8] = {b0.x, b0.y, b0.z, b0.w, b1.x, b1.y, b1.z, b1.w};
#pragma unroll
            for (int i = 0; i < 8; ++i)
#pragma unroll
                for (int j = 0; j < 8; ++j)
                    acc[i][j] += a[i] * b[j];
        }
        __syncthreads();
    }

#pragma unroll
    for (int i = 0; i < 8; ++i) {
        int m = m0 + ((i < 4) ? (ty * 4 + i) : (64 + ty * 4 + i - 4));
        float4 c0 = make_float4(acc[i][0], acc[i][1], acc[i][2], acc[i][3]);
        float4 c1 = make_float4(acc[i][4], acc[i][5], acc[i][6], acc[i][7]);
        *reinterpret_cast<float4*>(&C[(size_t)m * N + n0 + tx * 4])      = c0;
        *reinterpret_cast<float4*>(&C[(size_t)m * N + n0 + 64 + tx * 4]) = c1;
    }
}

// ---------------------------------------------------------------------------
// RMSNorm (over flat 2048) + RoPE (rotate-half, half=64) in place on q or k
// grid: (B*S, 2), block 256. sel 0 = q (cols 0..2047), sel 1 = k (2048..4095)
// ---------------------------------------------------------------------------
__global__ __launch_bounds__(256) void normrope_kernel(
    float* __restrict__ qkv, const float* __restrict__ qw,
    const float* __restrict__ kw) {
    const int row = blockIdx.x;
    const int sel = blockIdx.y;
    const int pos = row & (S_ - 1);
    float* p = qkv + (size_t)row * QKV_ + sel * 2048;
    const float* w = sel ? kw : qw;

    __shared__ float buf[2048];
    __shared__ float red[4];
    const int tid = threadIdx.x;

    float ss = 0.f;
#pragma unroll
    for (int i = 0; i < 2; ++i) {
        int f4 = tid + i * 256;
        float4 t = *reinterpret_cast<const float4*>(&p[f4 * 4]);
        *reinterpret_cast<float4*>(&buf[f4 * 4]) = t;
        ss += t.x * t.x + t.y * t.y + t.z * t.z + t.w * t.w;
    }
#pragma unroll
    for (int off = 32; off > 0; off >>= 1) ss += __shfl_xor(ss, off, 64);
    if ((tid & 63) == 0) red[tid >> 6] = ss;
    __syncthreads();
    float total = red[0] + red[1] + red[2] + red[3];
    float scale = rsqrtf(total * (1.f / 2048.f) + EPS_);

    const float kfreq = -0.14391156831212787f;  // -ln(10000)/64
#pragma unroll
    for (int i = 0; i < 2; ++i) {
        int f4 = tid + i * 256;
        int e  = f4 * 4;
        int d  = e & (HD_ - 1);
        int j  = d & 63;
        bool first = (d < 64);
        float4 xe = *reinterpret_cast<const float4*>(&buf[e]);
        float4 xp = *reinterpret_cast<const float4*>(&buf[e ^ 64]);
        float4 we = *reinterpret_cast<const float4*>(&w[e]);
        float4 wp = *reinterpret_cast<const float4*>(&w[e ^ 64]);
        float xs[4] = {xe.x, xe.y, xe.z, xe.w};
        float ps[4] = {xp.x, xp.y, xp.z, xp.w};
        float ws[4] = {we.x, we.y, we.z, we.w};
        float pw[4] = {wp.x, wp.y, wp.z, wp.w};
        float o[4];
#pragma unroll
        for (int u = 0; u < 4; ++u) {
            float inv_freq = expf((float)(j + u) * kfreq);
            float ang = (float)pos * inv_freq;
            float sn, cs;
            sincosf(ang, &sn, &cs);
            float a = xs[u] * scale * ws[u];
            float bb = ps[u] * scale * pw[u];
            o[u] = first ? (a * cs - bb * sn) : (a * cs + bb * sn);
        }
        float4 ov = make_float4(o[0], o[1], o[2], o[3]);
        *reinterpret_cast<float4*>(&p[e]) = ov;
    }
}

// ---------------------------------------------------------------------------
// Causal flash attention, fp32 SIMT. grid (S/32, B*NH), block 256.
// Q tile 32 rows in LDS; K/V tiles 32 rows in LDS; online softmax.
// Thread mapping: r = tid/8 (row), cg = tid%8.
//   scores: cols c = cg + 8j (j<4)  -> conflict-free Ks reads
//   PV/out: d = cg*4 + 32*ch + u    -> conflict-free Vs reads
// ---------------------------------------------------------------------------
__global__ __launch_bounds__(256) void attn_kernel(
    const float* __restrict__ qkv, float* __restrict__ aout) {
    const int qt = blockIdx.x;           // 0..63
    const int bh = blockIdx.y;           // 0..31
    const int b  = bh >> 4;
    const int h  = bh & (NH_ - 1);
    const int q0 = qt * 32;
    const int tid = threadIdx.x;
    const int r  = tid >> 3;
    const int cg = tid & 7;

    __shared__ float Qs[32][HD_ + 4];
    __shared__ float Ks[32][HD_ + 4];
    __shared__ float Vs[32][HD_ + 4];
    __shared__ float Ps[32][33];

    const size_t base = (size_t)(b * S_) * QKV_ + (size_t)h * HD_;

#pragma unroll
    for (int i = 0; i < 4; ++i) {
        int idx = tid + i * 256;
        int row = idx >> 5;
        int c4  = (idx & 31) * 4;
        float4 t = *reinterpret_cast<const float4*>(
            &qkv[base + (size_t)(q0 + row) * QKV_ + c4]);
        *reinterpret_cast<float4*>(&Qs[row][c4]) = t;
    }

    float O[4][4] = {};
    float m = -1e30f, l = 0.f;
    const float scale = 0.088388347648318447f;  // 1/sqrt(128)

    for (int kt = 0; kt <= qt; ++kt) {
        if (kt) __syncthreads();   // prior PV done before K/V overwrite
#pragma unroll
        for (int i = 0; i < 4; ++i) {
            int idx = tid + i * 256;
            int row = idx >> 5;
            int c4  = (idx & 31) * 4;
            size_t g = base + (size_t)(kt * 32 + row) * QKV_ + c4;
            float4 tk = *reinterpret_cast<const float4*>(&qkv[g + 2048]);
            *reinterpret_cast<float4*>(&Ks[row][c4]) = tk;
            float4 tv = *reinterpret_cast<const float4*>(&qkv[g + 4096]);
            *reinterpret_cast<float4*>(&Vs[row][c4]) = tv;
        }
        __syncthreads();

        float sc[4] = {0.f, 0.f, 0.f, 0.f};
#pragma unroll 8
        for (int k4 = 0; k4 < 32; ++k4) {
            float4 qv = *reinterpret_cast<const float4*>(&Qs[r][k4 * 4]);
#pragma unroll
            for (int j = 0; j < 4; ++j) {
                float4 kv =
                    *reinterpret_cast<const float4*>(&Ks[cg + 8 * j][k4 * 4]);
                sc[j] += qv.x * kv.x + qv.y * kv.y + qv.z * kv.z + qv.w * kv.w;
            }
        }
#pragma unroll
        for (int j = 0; j < 4; ++j) sc[j] *= scale;
        if (kt == qt) {
#pragma unroll
            for (int j = 0; j < 4; ++j)
                if (cg + 8 * j > r) sc[j] = -1e30f;
        }

        float mx = fmaxf(fmaxf(sc[0], sc[1]), fmaxf(sc[2], sc[3]));
        mx = fmaxf(mx, __shfl_xor(mx, 1, 64));
        mx = fmaxf(mx, __shfl_xor(mx, 2, 64));
        mx = fmaxf(mx, __shfl_xor(mx, 4, 64));
        float m_new = fmaxf(m, mx);
        float alpha = __expf(m - m_new);
        float p[4];
        float psum = 0.f;
#pragma unroll
        for (int j = 0; j < 4; ++j) {
            p[j] = __expf(sc[j] - m_new);
            psum += p[j];
        }
        psum += __shfl_xor(psum, 1, 64);
        psum += __shfl_xor(psum, 2, 64);
        psum += __shfl_xor(psum, 4, 64);
        l = l * alpha + psum;
        m = m_new;
#pragma unroll
        for (int j = 0; j < 4; ++j) Ps[r][cg + 8 * j] = p[j];
        __syncthreads();

#pragma unroll
        for (int ch = 0; ch < 4; ++ch)
#pragma unroll
            for (int u = 0; u < 4; ++u) O[ch][u] *= alpha;
#pragma unroll 4
        for (int c = 0; c < 32; ++c) {
            float pv = Ps[r][c];
#pragma unroll
            for (int ch = 0; ch < 4; ++ch) {
                float4 vv = *reinterpret_cast<const float4*>(
                    &Vs[c][cg * 4 + ch * 32]);
                O[ch][0] += pv * vv.x;
                O[ch][1] += pv * vv.y;
                O[ch][2] += pv * vv.z;
                O[ch][3] += pv * vv.w;
            }
        }
    }

    float inv_l = 1.f / l;
    const size_t orow = (size_t)(b * S_ + q0 + r) * (NH_ * HD_) + (size_t)h * HD_;
#pragma unroll
    for (int ch = 0; ch < 4; ++ch) {
        float4 o4 = make_float4(O[ch][0] * inv_l, O[ch][1] * inv_l,
                                O[ch][2] * inv_l, O[ch][3] * inv_l);
        *reinterpret_cast<float4*>(&aout[orow + cg * 4 + ch * 32]) = o4;
    }
}

// ---------------------------------------------------------------------------
extern "C" void kernel_launch(void* const* d_in, const int* in_sizes, int n_in,
                              void* d_out, int out_size, void* d_ws,
                              size_t ws_size, hipStream_t stream) {
    const float* x     = (const float*)d_in[0];
    const float* w_in  = (const float*)d_in[1];
    const float* w_out = (const float*)d_in[2];
    const float* qw    = (const float*)d_in[3];
    const float* kw    = (const float*)d_in[4];
    float* out = (float*)d_out;

    float* qkv  = (float*)d_ws;                            // [4096, 6144]
    float* attn = qkv + (size_t)(B_ * S_) * QKV_;          // [4096, 2048]

    const int M = B_ * S_;  // 4096
    dim3 blk(256);

    // qkv = x @ w_in^T   (M=4096, N=6144, K=2048)
    gemm_nt<<<dim3(QKV_ / BN, M / BM), blk, 0, stream>>>(x, w_in, qkv, M, QKV_,
                                                         HID_);
    // rmsnorm + rope on q and k, in place
    normrope_kernel<<<dim3(M, 2), blk, 0, stream>>>(qkv, qw, kw);
    // causal attention -> attn [4096, 2048]
    attn_kernel<<<dim3(S_ / 32, B_ * NH_), blk, 0, stream>>>(qkv, attn);
    // out = attn @ w_out^T  (M=4096, N=2048, K=2048)
    gemm_nt<<<dim3(HID_ / BN, M / BM), blk, 0, stream>>>(attn, w_out, out, M,
                                                         HID_, NH_ * HD_);
}

// Round 2
// 1739.864 us; speedup vs baseline: 1.8826x; 1.8826x over previous
//
#include <hip/hip_runtime.h>
#include <hip/hip_bf16.h>
#include <math.h>

#define B_   2
#define S_   2048
#define HID_ 2048
#define NH_  16
#define HD_  128
#define QKV_ (3 * NH_ * HD_)   // 6144
#define EPS_ 1e-5f

typedef __bf16 bf16x8 __attribute__((ext_vector_type(8)));
typedef __bf16 bf16x4 __attribute__((ext_vector_type(4)));
typedef float  f32x4  __attribute__((ext_vector_type(4)));

// ---------------------------------------------------------------------------
// fp32 -> bf16 cast (RNE via native __bf16 conversion). n4 = nelem/4.
// ---------------------------------------------------------------------------
__global__ __launch_bounds__(256) void cast_f32_bf16(
    const float* __restrict__ in, __bf16* __restrict__ out, int n4) {
    int i = blockIdx.x * 256 + threadIdx.x;
    if (i < n4) {
        float4 v = reinterpret_cast<const float4*>(in)[i];
        bf16x4 o = {(__bf16)v.x, (__bf16)v.y, (__bf16)v.z, (__bf16)v.w};
        reinterpret_cast<bf16x4*>(out)[i] = o;
    }
}

// ---------------------------------------------------------------------------
// bf16 MFMA GEMM (NT): C[M,N] = A[M,K] * B[N,K]^T, A/B bf16 row-major,
// fp32 accumulate. 128x128 block tile, BK=32, 256 threads = 4 waves,
// each wave owns a 64x64 quadrant = 4x4 grid of 16x16x32 MFMAs.
// Staging: global_load_lds width=16 (wave-uniform LDS base + lane*16).
// Fragment layouts (m89/m120-verified): A[m=lane&15][k=quad*8+j],
// B[n=lane&15][k=quad*8+j], D[m=quad*4+reg][n=lane&15].
// ---------------------------------------------------------------------------
__device__ __forceinline__ void gload_lds16(const __bf16* g, __bf16* l) {
    __builtin_amdgcn_global_load_lds(
        (const __attribute__((address_space(1))) void*)g,
        (__attribute__((address_space(3))) void*)l, 16, 0, 0);
}

template <typename OutT>
__global__ __launch_bounds__(256) void gemm_bt_mfma(
    const __bf16* __restrict__ A, const __bf16* __restrict__ Bm,
    OutT* __restrict__ C, int M, int N, int K) {
    __shared__ __bf16 As[128 * 32];   // [row][k] row-major, 8 KB
    __shared__ __bf16 Bs[128 * 32];

    const int tid  = threadIdx.x;
    const int w    = tid >> 6;        // wave 0..3
    const int lane = tid & 63;
    const int wh   = w >> 1;          // quadrant row
    const int ww   = w & 1;           // quadrant col
    const int lrow = lane & 15;
    const int quad = lane >> 4;
    const int m0 = blockIdx.y * 128;
    const int n0 = blockIdx.x * 128;

    f32x4 acc[4][4] = {};

    for (int k0 = 0; k0 < K; k0 += 32) {
        __syncthreads();  // prior iter's ds_reads done before LDS overwrite
#pragma unroll
        for (int t = 0; t < 2; ++t) {
            // chunk c covers 8 bf16: row = c>>2, kcol = (c&3)*8
            int c   = (w * 2 + t) * 64 + lane;
            int row = c >> 2;
            int kc  = (c & 3) * 8;
            // LDS base is wave-uniform; HW adds lane*16 bytes (= lane*8 elems)
            gload_lds16(&A[(size_t)(m0 + row) * K + k0 + kc],
                        &As[(w * 2 + t) * 512]);
            gload_lds16(&Bm[(size_t)(n0 + row) * K + k0 + kc],
                        &Bs[(w * 2 + t) * 512]);
        }
        __syncthreads();  // drains vmcnt (global_load_lds) + visibility

        bf16x8 af[4], bf[4];
#pragma unroll
        for (int i = 0; i < 4; ++i)
            af[i] = *reinterpret_cast<const bf16x8*>(
                &As[(wh * 64 + i * 16 + lrow) * 32 + quad * 8]);
#pragma unroll
        for (int j = 0; j < 4; ++j)
            bf[j] = *reinterpret_cast<const bf16x8*>(
                &Bs[(ww * 64 + j * 16 + lrow) * 32 + quad * 8]);
#pragma unroll
        for (int i = 0; i < 4; ++i)
#pragma unroll
            for (int j = 0; j < 4; ++j)
                acc[i][j] = __builtin_amdgcn_mfma_f32_16x16x32_bf16(
                    af[i], bf[j], acc[i][j], 0, 0, 0);
    }

#pragma unroll
    for (int i = 0; i < 4; ++i) {
#pragma unroll
        for (int r = 0; r < 4; ++r) {
            int row = m0 + wh * 64 + i * 16 + quad * 4 + r;
            size_t base = (size_t)row * N + n0 + ww * 64 + lrow;
#pragma unroll
            for (int j = 0; j < 4; ++j) {
                float v = acc[i][j][r];
                C[base + j * 16] = (OutT)v;
            }
        }
    }
}

// ---------------------------------------------------------------------------
// RMSNorm (flat 2048) + RoPE (rotate-half, half=64) in place on bf16 q or k.
// grid: (B*S, 2), block 256; each thread owns 8 contiguous elements.
// ---------------------------------------------------------------------------
__global__ __launch_bounds__(256) void normrope_kernel(
    __bf16* __restrict__ qkv, const float* __restrict__ qw,
    const float* __restrict__ kw) {
    const int row = blockIdx.x;
    const int sel = blockIdx.y;
    const int pos = row & (S_ - 1);
    __bf16* p = qkv + (size_t)row * QKV_ + sel * 2048;
    const float* w = sel ? kw : qw;

    __shared__ float buf[2048];
    __shared__ float red[4];
    const int tid = threadIdx.x;
    const int e   = tid * 8;

    bf16x8 t = *reinterpret_cast<const bf16x8*>(&p[e]);
    float xs[8];
    float ss = 0.f;
#pragma unroll
    for (int u = 0; u < 8; ++u) {
        xs[u] = (float)t[u];
        buf[e + u] = xs[u];
        ss += xs[u] * xs[u];
    }
#pragma unroll
    for (int off = 32; off > 0; off >>= 1) ss += __shfl_xor(ss, off, 64);
    if ((tid & 63) == 0) red[tid >> 6] = ss;
    __syncthreads();
    float total = red[0] + red[1] + red[2] + red[3];
    float scale = rsqrtf(total * (1.f / 2048.f) + EPS_);

    const float kfreq = -0.14391156831212787f;  // -ln(10000)/64
    const int jbase = e & 63;
    const bool first = (e & 127) < 64;
    const int ep = e ^ 64;

    float ps[8], ws[8], pw[8];
#pragma unroll
    for (int u = 0; u < 8; ++u) ps[u] = buf[ep + u];
    float4 w0 = *reinterpret_cast<const float4*>(&w[e]);
    float4 w1 = *reinterpret_cast<const float4*>(&w[e + 4]);
    float4 p0 = *reinterpret_cast<const float4*>(&w[ep]);
    float4 p1 = *reinterpret_cast<const float4*>(&w[ep + 4]);
    ws[0]=w0.x; ws[1]=w0.y; ws[2]=w0.z; ws[3]=w0.w;
    ws[4]=w1.x; ws[5]=w1.y; ws[6]=w1.z; ws[7]=w1.w;
    pw[0]=p0.x; pw[1]=p0.y; pw[2]=p0.z; pw[3]=p0.w;
    pw[4]=p1.x; pw[5]=p1.y; pw[6]=p1.z; pw[7]=p1.w;

    bf16x8 o8;
#pragma unroll
    for (int u = 0; u < 8; ++u) {
        float inv_freq = expf((float)(jbase + u) * kfreq);
        float ang = (float)pos * inv_freq;
        float sn, cs;
        sincosf(ang, &sn, &cs);
        float a  = xs[u] * scale * ws[u];
        float bb = ps[u] * scale * pw[u];
        float o  = first ? (a * cs - bb * sn) : (a * cs + bb * sn);
        o8[u] = (__bf16)o;
    }
    *reinterpret_cast<bf16x8*>(&p[e]) = o8;
}

// ---------------------------------------------------------------------------
// Causal flash attention, fp32 SIMT compute, bf16 in/out.
// grid (S/32, B*NH), block 256. Unchanged logic from round 1.
// ---------------------------------------------------------------------------
__global__ __launch_bounds__(256) void attn_kernel(
    const __bf16* __restrict__ qkv, __bf16* __restrict__ aout) {
    const int qt = blockIdx.x;           // 0..63
    const int bh = blockIdx.y;           // 0..31
    const int b  = bh >> 4;
    const int h  = bh & (NH_ - 1);
    const int q0 = qt * 32;
    const int tid = threadIdx.x;
    const int r  = tid >> 3;
    const int cg = tid & 7;

    __shared__ float Qs[32][HD_ + 4];
    __shared__ float Ks[32][HD_ + 4];
    __shared__ float Vs[32][HD_ + 4];
    __shared__ float Ps[32][33];

    const size_t base = (size_t)(b * S_) * QKV_ + (size_t)h * HD_;

    // stage Q: 32 rows x 128 cols bf16 = 512 chunks of 8; 2 per thread
#pragma unroll
    for (int i = 0; i < 2; ++i) {
        int idx = tid + i * 256;
        int row = idx >> 4;
        int c8  = (idx & 15) * 8;
        bf16x8 t = *reinterpret_cast<const bf16x8*>(
            &qkv[base + (size_t)(q0 + row) * QKV_ + c8]);
#pragma unroll
        for (int u = 0; u < 8; ++u) Qs[row][c8 + u] = (float)t[u];
    }

    float O[4][4] = {};
    float m = -1e30f, l = 0.f;
    const float scale = 0.088388347648318447f;  // 1/sqrt(128)

    for (int kt = 0; kt <= qt; ++kt) {
        if (kt) __syncthreads();   // prior PV done before K/V overwrite
#pragma unroll
        for (int i = 0; i < 2; ++i) {
            int idx = tid + i * 256;
            int row = idx >> 4;
            int c8  = (idx & 15) * 8;
            size_t g = base + (size_t)(kt * 32 + row) * QKV_ + c8;
            bf16x8 tk = *reinterpret_cast<const bf16x8*>(&qkv[g + 2048]);
            bf16x8 tv = *reinterpret_cast<const bf16x8*>(&qkv[g + 4096]);
#pragma unroll
            for (int u = 0; u < 8; ++u) {
                Ks[row][c8 + u] = (float)tk[u];
                Vs[row][c8 + u] = (float)tv[u];
            }
        }
        __syncthreads();

        float sc[4] = {0.f, 0.f, 0.f, 0.f};
#pragma unroll 8
        for (int k4 = 0; k4 < 32; ++k4) {
            float4 qv = *reinterpret_cast<const float4*>(&Qs[r][k4 * 4]);
#pragma unroll
            for (int j = 0; j < 4; ++j) {
                float4 kv =
                    *reinterpret_cast<const float4*>(&Ks[cg + 8 * j][k4 * 4]);
                sc[j] += qv.x * kv.x + qv.y * kv.y + qv.z * kv.z + qv.w * kv.w;
            }
        }
#pragma unroll
        for (int j = 0; j < 4; ++j) sc[j] *= scale;
        if (kt == qt) {
#pragma unroll
            for (int j = 0; j < 4; ++j)
                if (cg + 8 * j > r) sc[j] = -1e30f;
        }

        float mx = fmaxf(fmaxf(sc[0], sc[1]), fmaxf(sc[2], sc[3]));
        mx = fmaxf(mx, __shfl_xor(mx, 1, 64));
        mx = fmaxf(mx, __shfl_xor(mx, 2, 64));
        mx = fmaxf(mx, __shfl_xor(mx, 4, 64));
        float m_new = fmaxf(m, mx);
        float alpha = __expf(m - m_new);
        float p[4];
        float psum = 0.f;
#pragma unroll
        for (int j = 0; j < 4; ++j) {
            p[j] = __expf(sc[j] - m_new);
            psum += p[j];
        }
        psum += __shfl_xor(psum, 1, 64);
        psum += __shfl_xor(psum, 2, 64);
        psum += __shfl_xor(psum, 4, 64);
        l = l * alpha + psum;
        m = m_new;
#pragma unroll
        for (int j = 0; j < 4; ++j) Ps[r][cg + 8 * j] = p[j];
        __syncthreads();

#pragma unroll
        for (int ch = 0; ch < 4; ++ch)
#pragma unroll
            for (int u = 0; u < 4; ++u) O[ch][u] *= alpha;
#pragma unroll 4
        for (int c = 0; c < 32; ++c) {
            float pv = Ps[r][c];
#pragma unroll
            for (int ch = 0; ch < 4; ++ch) {
                float4 vv = *reinterpret_cast<const float4*>(
                    &Vs[c][cg * 4 + ch * 32]);
                O[ch][0] += pv * vv.x;
                O[ch][1] += pv * vv.y;
                O[ch][2] += pv * vv.z;
                O[ch][3] += pv * vv.w;
            }
        }
    }

    float inv_l = 1.f / l;
    const size_t orow = (size_t)(b * S_ + q0 + r) * (NH_ * HD_) + (size_t)h * HD_;
#pragma unroll
    for (int ch = 0; ch < 4; ++ch) {
        bf16x4 o4 = {(__bf16)(O[ch][0] * inv_l), (__bf16)(O[ch][1] * inv_l),
                     (__bf16)(O[ch][2] * inv_l), (__bf16)(O[ch][3] * inv_l)};
        *reinterpret_cast<bf16x4*>(&aout[orow + cg * 4 + ch * 32]) = o4;
    }
}

// ---------------------------------------------------------------------------
extern "C" void kernel_launch(void* const* d_in, const int* in_sizes, int n_in,
                              void* d_out, int out_size, void* d_ws,
                              size_t ws_size, hipStream_t stream) {
    const float* x     = (const float*)d_in[0];
    const float* w_in  = (const float*)d_in[1];
    const float* w_out = (const float*)d_in[2];
    const float* qw    = (const float*)d_in[3];
    const float* kw    = (const float*)d_in[4];
    float* out = (float*)d_out;

    const int M = B_ * S_;  // 4096
    // workspace layout (bytes): peak 96 MiB
    //   [0, 48M)    qkv_bf16   [4096, 6144]
    //   [48M, 56M)  w_out_bf16 [2048, 2048]   (alive whole call)
    //   [56M, 72M)  x_bf16     [4096, 2048] -> reused as attn_bf16 after GEMM1
    //   [72M, 96M)  w_in_bf16  [6144, 2048]   (dead after GEMM1)
    char* ws = (char*)d_ws;
    __bf16* qkv_b   = (__bf16*)(ws);
    __bf16* w_out_b = (__bf16*)(ws + (size_t)50331648);
    __bf16* x_b     = (__bf16*)(ws + (size_t)58720256);
    __bf16* attn_b  = x_b;  // alias: x_bf16 dead after GEMM1
    __bf16* w_in_b  = (__bf16*)(ws + (size_t)75497472);

    dim3 blk(256);

    // casts
    {
        int n4;
        n4 = (M * HID_) / 4;          // x: 2,097,152
        cast_f32_bf16<<<dim3((n4 + 255) / 256), blk, 0, stream>>>(x, x_b, n4);
        n4 = (QKV_ * HID_) / 4;       // w_in: 3,145,728
        cast_f32_bf16<<<dim3((n4 + 255) / 256), blk, 0, stream>>>(w_in, w_in_b, n4);
        n4 = (HID_ * NH_ * HD_) / 4;  // w_out: 1,048,576
        cast_f32_bf16<<<dim3((n4 + 255) / 256), blk, 0, stream>>>(w_out, w_out_b, n4);
    }

    // qkv = x @ w_in^T   (M=4096, N=6144, K=2048), bf16 out
    gemm_bt_mfma<__bf16><<<dim3(QKV_ / 128, M / 128), blk, 0, stream>>>(
        x_b, w_in_b, qkv_b, M, QKV_, HID_);
    // rmsnorm + rope on q and k, in place (bf16)
    normrope_kernel<<<dim3(M, 2), blk, 0, stream>>>(qkv_b, qw, kw);
    // causal attention -> attn_bf16 [4096, 2048]
    attn_kernel<<<dim3(S_ / 32, B_ * NH_), blk, 0, stream>>>(qkv_b, attn_b);
    // out = attn @ w_out^T  (M=4096, N=2048, K=2048), fp32 out
    gemm_bt_mfma<float><<<dim3(HID_ / 128, M / 128), blk, 0, stream>>>(
        attn_b, w_out_b, out, M, HID_, NH_ * HD_);
}

// Round 3
// 554.505 us; speedup vs baseline: 5.9070x; 3.1377x over previous
//
#include <hip/hip_runtime.h>
#include <hip/hip_bf16.h>
#include <math.h>

#define B_   2
#define S_   2048
#define HID_ 2048
#define NH_  16
#define HD_  128
#define QKV_ (3 * NH_ * HD_)   // 6144
#define EPS_ 1e-5f

typedef __bf16 bf16x8 __attribute__((ext_vector_type(8)));
typedef __bf16 bf16x4 __attribute__((ext_vector_type(4)));
typedef __bf16 bf16x2 __attribute__((ext_vector_type(2)));
typedef float  f32x4  __attribute__((ext_vector_type(4)));

// ---------------------------------------------------------------------------
// fp32 -> bf16 cast (RNE). n4 = nelem/4.
// ---------------------------------------------------------------------------
__global__ __launch_bounds__(256) void cast_f32_bf16(
    const float* __restrict__ in, __bf16* __restrict__ out, int n4) {
    int i = blockIdx.x * 256 + threadIdx.x;
    if (i < n4) {
        float4 v = reinterpret_cast<const float4*>(in)[i];
        bf16x4 o = {(__bf16)v.x, (__bf16)v.y, (__bf16)v.z, (__bf16)v.w};
        reinterpret_cast<bf16x4*>(out)[i] = o;
    }
}

// ---------------------------------------------------------------------------
// bf16 MFMA GEMM (NT): C[M,N] = A[M,K] * B[N,K]^T  (unchanged, round-2 proven)
// ---------------------------------------------------------------------------
__device__ __forceinline__ void gload_lds16(const __bf16* g, __bf16* l) {
    __builtin_amdgcn_global_load_lds(
        (const __attribute__((address_space(1))) void*)g,
        (__attribute__((address_space(3))) void*)l, 16, 0, 0);
}

template <typename OutT>
__global__ __launch_bounds__(256) void gemm_bt_mfma(
    const __bf16* __restrict__ A, const __bf16* __restrict__ Bm,
    OutT* __restrict__ C, int M, int N, int K) {
    __shared__ __bf16 As[128 * 32];
    __shared__ __bf16 Bs[128 * 32];

    const int tid  = threadIdx.x;
    const int w    = tid >> 6;
    const int lane = tid & 63;
    const int wh   = w >> 1;
    const int ww   = w & 1;
    const int lrow = lane & 15;
    const int quad = lane >> 4;
    const int m0 = blockIdx.y * 128;
    const int n0 = blockIdx.x * 128;

    f32x4 acc[4][4] = {};

    for (int k0 = 0; k0 < K; k0 += 32) {
        __syncthreads();
#pragma unroll
        for (int t = 0; t < 2; ++t) {
            int c   = (w * 2 + t) * 64 + lane;
            int row = c >> 2;
            int kc  = (c & 3) * 8;
            gload_lds16(&A[(size_t)(m0 + row) * K + k0 + kc],
                        &As[(w * 2 + t) * 512]);
            gload_lds16(&Bm[(size_t)(n0 + row) * K + k0 + kc],
                        &Bs[(w * 2 + t) * 512]);
        }
        __syncthreads();

        bf16x8 af[4], bf[4];
#pragma unroll
        for (int i = 0; i < 4; ++i)
            af[i] = *reinterpret_cast<const bf16x8*>(
                &As[(wh * 64 + i * 16 + lrow) * 32 + quad * 8]);
#pragma unroll
        for (int j = 0; j < 4; ++j)
            bf[j] = *reinterpret_cast<const bf16x8*>(
                &Bs[(ww * 64 + j * 16 + lrow) * 32 + quad * 8]);
#pragma unroll
        for (int i = 0; i < 4; ++i)
#pragma unroll
            for (int j = 0; j < 4; ++j)
                acc[i][j] = __builtin_amdgcn_mfma_f32_16x16x32_bf16(
                    af[i], bf[j], acc[i][j], 0, 0, 0);
    }

#pragma unroll
    for (int i = 0; i < 4; ++i) {
#pragma unroll
        for (int r = 0; r < 4; ++r) {
            int row = m0 + wh * 64 + i * 16 + quad * 4 + r;
            size_t base = (size_t)row * N + n0 + ww * 64 + lrow;
#pragma unroll
            for (int j = 0; j < 4; ++j) {
                float v = acc[i][j][r];
                C[base + j * 16] = (OutT)v;
            }
        }
    }
}

// ---------------------------------------------------------------------------
// RMSNorm (flat 2048) + RoPE in place on bf16 q or k. (unchanged)
// ---------------------------------------------------------------------------
__global__ __launch_bounds__(256) void normrope_kernel(
    __bf16* __restrict__ qkv, const float* __restrict__ qw,
    const float* __restrict__ kw) {
    const int row = blockIdx.x;
    const int sel = blockIdx.y;
    const int pos = row & (S_ - 1);
    __bf16* p = qkv + (size_t)row * QKV_ + sel * 2048;
    const float* w = sel ? kw : qw;

    __shared__ float buf[2048];
    __shared__ float red[4];
    const int tid = threadIdx.x;
    const int e   = tid * 8;

    bf16x8 t = *reinterpret_cast<const bf16x8*>(&p[e]);
    float xs[8];
    float ss = 0.f;
#pragma unroll
    for (int u = 0; u < 8; ++u) {
        xs[u] = (float)t[u];
        buf[e + u] = xs[u];
        ss += xs[u] * xs[u];
    }
#pragma unroll
    for (int off = 32; off > 0; off >>= 1) ss += __shfl_xor(ss, off, 64);
    if ((tid & 63) == 0) red[tid >> 6] = ss;
    __syncthreads();
    float total = red[0] + red[1] + red[2] + red[3];
    float scale = rsqrtf(total * (1.f / 2048.f) + EPS_);

    const float kfreq = -0.14391156831212787f;  // -ln(10000)/64
    const int jbase = e & 63;
    const bool first = (e & 127) < 64;
    const int ep = e ^ 64;

    float ps[8], ws[8], pw[8];
#pragma unroll
    for (int u = 0; u < 8; ++u) ps[u] = buf[ep + u];
    float4 w0 = *reinterpret_cast<const float4*>(&w[e]);
    float4 w1 = *reinterpret_cast<const float4*>(&w[e + 4]);
    float4 p0 = *reinterpret_cast<const float4*>(&w[ep]);
    float4 p1 = *reinterpret_cast<const float4*>(&w[ep + 4]);
    ws[0]=w0.x; ws[1]=w0.y; ws[2]=w0.z; ws[3]=w0.w;
    ws[4]=w1.x; ws[5]=w1.y; ws[6]=w1.z; ws[7]=w1.w;
    pw[0]=p0.x; pw[1]=p0.y; pw[2]=p0.z; pw[3]=p0.w;
    pw[4]=p1.x; pw[5]=p1.y; pw[6]=p1.z; pw[7]=p1.w;

    bf16x8 o8;
#pragma unroll
    for (int u = 0; u < 8; ++u) {
        float inv_freq = expf((float)(jbase + u) * kfreq);
        float ang = (float)pos * inv_freq;
        float sn, cs;
        sincosf(ang, &sn, &cs);
        float a  = xs[u] * scale * ws[u];
        float bb = ps[u] * scale * pw[u];
        float o  = first ? (a * cs - bb * sn) : (a * cs + bb * sn);
        o8[u] = (__bf16)o;
    }
    *reinterpret_cast<bf16x8*>(&p[e]) = o8;
}

// ---------------------------------------------------------------------------
// MFMA flash attention. grid (S/128=16 [qt reversed], B*NH=32), block 256.
// Per block: 128 Q rows of one (b,h). Wave w owns rows [w*32, w*32+32).
// K/V tiles of 32 keys staged in LDS each iteration; V transposed (Vt[d][key])
// so PV B-frags are contiguous ds_read_b128. P crosses C->A layout via
// per-wave LDS round-trip. Softmax state per-lane (C-layout rows), reduced
// across 16-lane column groups via shfl_xor.
// Layouts (round-2-GEMM-proven): A[m=lane&15][k=quad*8+j],
// B[n=lane&15][k=quad*8+j], D[m=quad*4+reg][n=lane&15].
// ---------------------------------------------------------------------------
#define KPAD 136   // 128+8: breaks pow2 bank stride, keeps 16B alignment
#define VPAD 40    // 32+8

__global__ __launch_bounds__(256) void attn_mfma(
    const __bf16* __restrict__ qkv, __bf16* __restrict__ aout) {
    const int qt  = (int)gridDim.x - 1 - (int)blockIdx.x;  // heavy blocks first
    const int bh  = blockIdx.y;
    const int b   = bh >> 4;
    const int h   = bh & (NH_ - 1);
    const int q0  = qt * 128;
    const int tid = threadIdx.x;
    const int w    = tid >> 6;
    const int lane = tid & 63;
    const int lrow = lane & 15;
    const int quad = lane >> 4;

    __shared__ __bf16 Ks[32 * KPAD];      // [key][kdim]
    __shared__ __bf16 Vt[128 * VPAD];     // [d][key]
    __shared__ __bf16 Ps[4][32 * VPAD];   // per-wave P [qrow][key]

    const size_t base = (size_t)(b * S_) * QKV_ + (size_t)h * HD_;

    // Resident Q A-frags: qf[mt][kc] covers rows q0+w*32+mt*16+(lane&15),
    // k-chunk kc: elements [kc*32 + quad*8 .. +7]
    bf16x8 qf[2][4];
#pragma unroll
    for (int mt = 0; mt < 2; ++mt)
#pragma unroll
        for (int kc = 0; kc < 4; ++kc)
            qf[mt][kc] = *reinterpret_cast<const bf16x8*>(
                &qkv[base + (size_t)(q0 + w * 32 + mt * 16 + lrow) * QKV_ +
                     kc * 32 + quad * 8]);

    f32x4 o[2][8] = {};           // [mt][dtile]: rows quad*4+r, col dt*16+lrow
    float ms[2][4], ls[2][4];     // per-lane softmax state, row = quad*4+r
#pragma unroll
    for (int mt = 0; mt < 2; ++mt)
#pragma unroll
        for (int r = 0; r < 4; ++r) { ms[mt][r] = -1e30f; ls[mt][r] = 0.f; }

    const int ktmax_blk = qt * 4 + 3;
    const int ktmax_w   = qt * 4 + w;     // wave's last (diagonal) tile
    const float scale = 0.088388347648318447f;  // 1/sqrt(128)

    const int vkey2 = (tid & 15) * 2;     // V staging: key pair
    const int vd0   = (tid >> 4) * 8;     // 8 d-values

    for (int kt = 0; kt <= ktmax_blk; ++kt) {
        __syncthreads();  // prior iter's frag reads done before overwrite
        // stage K tile [32 keys][128 k], row-major, padded
#pragma unroll
        for (int i = 0; i < 2; ++i) {
            int c = tid + i * 256;
            int key = c >> 4, kc8 = (c & 15) * 8;
            bf16x8 t = *reinterpret_cast<const bf16x8*>(
                &qkv[base + 2048 + (size_t)(kt * 32 + key) * QKV_ + kc8]);
            *reinterpret_cast<bf16x8*>(&Ks[key * KPAD + kc8]) = t;
        }
        // stage V transposed: Vt[d][key], pair-packed b32 writes
        {
            const __bf16* vg =
                &qkv[base + 4096 + (size_t)(kt * 32 + vkey2) * QKV_ + vd0];
            bf16x8 v0 = *reinterpret_cast<const bf16x8*>(vg);
            bf16x8 v1 = *reinterpret_cast<const bf16x8*>(vg + QKV_);
#pragma unroll
            for (int u = 0; u < 8; ++u) {
                bf16x2 pr = {v0[u], v1[u]};
                *reinterpret_cast<bf16x2*>(&Vt[(vd0 + u) * VPAD + vkey2]) = pr;
            }
        }
        __syncthreads();

        if (kt <= ktmax_w) {   // wave-uniform causal skip
            // S = Q K^T : sc[mt][jt], keys jt*16+lrow, rows quad*4+r
            f32x4 sc[2][2] = {};
#pragma unroll
            for (int kc = 0; kc < 4; ++kc) {
                bf16x8 kf0 = *reinterpret_cast<const bf16x8*>(
                    &Ks[lrow * KPAD + kc * 32 + quad * 8]);
                bf16x8 kf1 = *reinterpret_cast<const bf16x8*>(
                    &Ks[(16 + lrow) * KPAD + kc * 32 + quad * 8]);
                sc[0][0] = __builtin_amdgcn_mfma_f32_16x16x32_bf16(
                    qf[0][kc], kf0, sc[0][0], 0, 0, 0);
                sc[0][1] = __builtin_amdgcn_mfma_f32_16x16x32_bf16(
                    qf[0][kc], kf1, sc[0][1], 0, 0, 0);
                sc[1][0] = __builtin_amdgcn_mfma_f32_16x16x32_bf16(
                    qf[1][kc], kf0, sc[1][0], 0, 0, 0);
                sc[1][1] = __builtin_amdgcn_mfma_f32_16x16x32_bf16(
                    qf[1][kc], kf1, sc[1][1], 0, 0, 0);
            }
            const bool diag = (kt == ktmax_w);
#pragma unroll
            for (int mt = 0; mt < 2; ++mt) {
                float p0[4], p1[4], alpha[4];
#pragma unroll
                for (int r = 0; r < 4; ++r) {
                    float s0 = sc[mt][0][r] * scale;
                    float s1 = sc[mt][1][r] * scale;
                    if (diag) {
                        int qrow = q0 + w * 32 + mt * 16 + quad * 4 + r;
                        if (kt * 32 + lrow > qrow)      s0 = -1e30f;
                        if (kt * 32 + 16 + lrow > qrow) s1 = -1e30f;
                    }
                    float mx = fmaxf(s0, s1);
                    mx = fmaxf(mx, __shfl_xor(mx, 1, 64));
                    mx = fmaxf(mx, __shfl_xor(mx, 2, 64));
                    mx = fmaxf(mx, __shfl_xor(mx, 4, 64));
                    mx = fmaxf(mx, __shfl_xor(mx, 8, 64));
                    float mnew = fmaxf(ms[mt][r], mx);
                    alpha[r] = __expf(ms[mt][r] - mnew);
                    ms[mt][r] = mnew;
                    p0[r] = __expf(s0 - mnew);
                    p1[r] = __expf(s1 - mnew);
                    float psum = p0[r] + p1[r];
                    psum += __shfl_xor(psum, 1, 64);
                    psum += __shfl_xor(psum, 2, 64);
                    psum += __shfl_xor(psum, 4, 64);
                    psum += __shfl_xor(psum, 8, 64);
                    ls[mt][r] = ls[mt][r] * alpha[r] + psum;
                }
                // P: C-layout -> LDS (per-wave buffer, no barrier needed)
#pragma unroll
                for (int r = 0; r < 4; ++r) {
                    Ps[w][(mt * 16 + quad * 4 + r) * VPAD + lrow] = (__bf16)p0[r];
                    Ps[w][(mt * 16 + quad * 4 + r) * VPAD + 16 + lrow] =
                        (__bf16)p1[r];
                }
                // rescale O
#pragma unroll
                for (int dt = 0; dt < 8; ++dt)
#pragma unroll
                    for (int r = 0; r < 4; ++r) o[mt][dt][r] *= alpha[r];
            }
            // PV: A = P (A-layout from LDS), B = Vt rows (contiguous keys)
            bf16x8 pf0 = *reinterpret_cast<const bf16x8*>(
                &Ps[w][lrow * VPAD + quad * 8]);
            bf16x8 pf1 = *reinterpret_cast<const bf16x8*>(
                &Ps[w][(16 + lrow) * VPAD + quad * 8]);
#pragma unroll
            for (int dt = 0; dt < 8; ++dt) {
                bf16x8 vf = *reinterpret_cast<const bf16x8*>(
                    &Vt[(dt * 16 + lrow) * VPAD + quad * 8]);
                o[0][dt] = __builtin_amdgcn_mfma_f32_16x16x32_bf16(
                    pf0, vf, o[0][dt], 0, 0, 0);
                o[1][dt] = __builtin_amdgcn_mfma_f32_16x16x32_bf16(
                    pf1, vf, o[1][dt], 0, 0, 0);
            }
        }
    }

    // epilogue: O / l -> aout[b, q, h*128 + d]
#pragma unroll
    for (int mt = 0; mt < 2; ++mt) {
#pragma unroll
        for (int r = 0; r < 4; ++r) {
            float invl = 1.f / ls[mt][r];
            size_t row = (size_t)(b * S_ + q0 + w * 32 + mt * 16 + quad * 4 + r);
            size_t ob = row * (NH_ * HD_) + (size_t)h * HD_ + lrow;
#pragma unroll
            for (int dt = 0; dt < 8; ++dt)
                aout[ob + dt * 16] = (__bf16)(o[mt][dt][r] * invl);
        }
    }
}

// ---------------------------------------------------------------------------
extern "C" void kernel_launch(void* const* d_in, const int* in_sizes, int n_in,
                              void* d_out, int out_size, void* d_ws,
                              size_t ws_size, hipStream_t stream) {
    const float* x     = (const float*)d_in[0];
    const float* w_in  = (const float*)d_in[1];
    const float* w_out = (const float*)d_in[2];
    const float* qw    = (const float*)d_in[3];
    const float* kw    = (const float*)d_in[4];
    float* out = (float*)d_out;

    const int M = B_ * S_;  // 4096
    // workspace (bytes), peak 96 MiB:
    //   [0,48M) qkv_bf16 | [48M,56M) w_out_bf16 | [56M,72M) x_bf16/attn_bf16
    //   [72M,96M) w_in_bf16
    char* ws = (char*)d_ws;
    __bf16* qkv_b   = (__bf16*)(ws);
    __bf16* w_out_b = (__bf16*)(ws + (size_t)50331648);
    __bf16* x_b     = (__bf16*)(ws + (size_t)58720256);
    __bf16* attn_b  = x_b;  // x_bf16 dead after GEMM1
    __bf16* w_in_b  = (__bf16*)(ws + (size_t)75497472);

    dim3 blk(256);

    {
        int n4;
        n4 = (M * HID_) / 4;
        cast_f32_bf16<<<dim3((n4 + 255) / 256), blk, 0, stream>>>(x, x_b, n4);
        n4 = (QKV_ * HID_) / 4;
        cast_f32_bf16<<<dim3((n4 + 255) / 256), blk, 0, stream>>>(w_in, w_in_b, n4);
        n4 = (HID_ * NH_ * HD_) / 4;
        cast_f32_bf16<<<dim3((n4 + 255) / 256), blk, 0, stream>>>(w_out, w_out_b, n4);
    }

    // qkv = x @ w_in^T   (4096 x 6144 x 2048)
    gemm_bt_mfma<__bf16><<<dim3(QKV_ / 128, M / 128), blk, 0, stream>>>(
        x_b, w_in_b, qkv_b, M, QKV_, HID_);
    // rmsnorm + rope on q and k, in place
    normrope_kernel<<<dim3(M, 2), blk, 0, stream>>>(qkv_b, qw, kw);
    // causal MFMA flash attention -> attn_bf16 [4096, 2048]
    attn_mfma<<<dim3(S_ / 128, B_ * NH_), blk, 0, stream>>>(qkv_b, attn_b);
    // out = attn @ w_out^T  (4096 x 2048 x 2048), fp32 out
    gemm_bt_mfma<float><<<dim3(HID_ / 128, M / 128), blk, 0, stream>>>(
        attn_b, w_out_b, out, M, HID_, NH_ * HD_);
}